// Round 9
// baseline (1173.884 us; speedup 1.0000x reference)
//
#include <hip/hip_runtime.h>

#define EPS 1e-6f

typedef __attribute__((ext_vector_type(8))) short bf16x8;
typedef __attribute__((ext_vector_type(4))) float f32x4;
typedef __attribute__((ext_vector_type(8))) unsigned short ushort8;

#define AS1(p) ((const __attribute__((address_space(1))) void*)(p))
#define AS3(p) ((__attribute__((address_space(3))) void*)(p))

__device__ inline unsigned int fkey(float f) {
  unsigned int u = __float_as_uint(f);
  return (u & 0x80000000u) ? ~u : (u | 0x80000000u);
}
// inverse of fkey: recover the exact fp32 bits
__device__ inline float inv_fkey(unsigned int k) {
  unsigned int u = (k & 0x80000000u) ? (k & 0x7fffffffu) : ~k;
  return __uint_as_float(u);
}

__device__ inline unsigned long long shfl_xor_u64(unsigned long long v, int mask) {
  unsigned int lo = (unsigned int)(v & 0xffffffffull);
  unsigned int hi = (unsigned int)(v >> 32);
  lo = (unsigned int)__shfl_xor((int)lo, mask);
  hi = (unsigned int)__shfl_xor((int)hi, mask);
  return (((unsigned long long)hi) << 32) | lo;
}

__device__ inline unsigned short f2bf(float f) {  // RNE fp32 -> bf16
  unsigned int u = __float_as_uint(f);
  u += 0x7fffu + ((u >> 16) & 1u);
  return (unsigned short)(u >> 16);
}
__device__ inline float bf2f(unsigned short h) {
  return __uint_as_float(((unsigned int)h) << 16);
}

// LDS byte-offset of a __shared__ address (AS3 pointers are 32-bit)
__device__ inline unsigned lds_off(const void* p) {
  return (unsigned)(unsigned long long)(__attribute__((address_space(3))) const void*)p;
}

// asm ds_read_b128 with immediate offset: compiler-untracked (we control lgkmcnt)
template<int OFF>
__device__ inline bf16x8 ds_read128(unsigned addr) {
  bf16x8 r;
  asm volatile("ds_read_b128 %0, %1 offset:%2" : "=v"(r) : "v"(addr), "i"(OFF));
  return r;
}

// asm global f32 load with immediate offset (keeps compiler vmcnt accounting clean)
template<int OFF>
__device__ inline float gload_f32(unsigned long long a) {
  float r;
  asm volatile("global_load_dword %0, %1, off offset:%2" : "=v"(r) : "v"(a), "i"(OFF));
  return r;
}

// ---------------- prep: splits + codebook norms + loss zero (one kernel) ----------------
__global__ __launch_bounds__(256) void prep_kernel(
    const float* __restrict__ x, const float* __restrict__ cbs,
    unsigned short* __restrict__ Rhi, unsigned short* __restrict__ Rlo,
    unsigned short* __restrict__ CBhi, unsigned short* __restrict__ CBlo,
    float* __restrict__ cbsq, float* __restrict__ loss_out) {
  constexpr size_t M = 32768, D = 512, C = 1024, Q = 8;
  const size_t nthreads = (size_t)gridDim.x * 256;
  const size_t gtid = (size_t)blockIdx.x * 256 + threadIdx.x;
  const int lane = threadIdx.x & 63;
  const int w = threadIdx.x >> 6;

  for (size_t i = gtid; i < M * D / 8; i += nthreads) {
    size_t off = i * 8;
    float4 v0 = *(const float4*)(x + off);
    float4 v1 = *(const float4*)(x + off + 4);
    float v[8] = {v0.x, v0.y, v0.z, v0.w, v1.x, v1.y, v1.z, v1.w};
    ushort8 h, l;
    #pragma unroll
    for (int j = 0; j < 8; j++) {
      unsigned short hh = f2bf(v[j]);
      h[j] = hh;
      l[j] = f2bf(v[j] - bf2f(hh));
    }
    *(ushort8*)(Rhi + off) = h;
    *(ushort8*)(Rlo + off) = l;
  }
  for (size_t i = gtid; i < Q * C * D / 8; i += nthreads) {
    size_t off = i * 8;
    float4 v0 = *(const float4*)(cbs + off);
    float4 v1 = *(const float4*)(cbs + off + 4);
    float v[8] = {v0.x, v0.y, v0.z, v0.w, v1.x, v1.y, v1.z, v1.w};
    ushort8 h, l;
    #pragma unroll
    for (int j = 0; j < 8; j++) {
      unsigned short hh = f2bf(v[j]);
      h[j] = hh;
      l[j] = f2bf(v[j] - bf2f(hh));
    }
    *(ushort8*)(CBhi + off) = h;
    *(ushort8*)(CBlo + off) = l;
  }
  for (int row = blockIdx.x * 4 + w; row < (int)(Q * C); row += gridDim.x * 4) {
    const float4* p = (const float4*)(cbs + (size_t)row * 512);
    float4 v0 = p[lane];
    float4 v1 = p[lane + 64];
    float s = v0.x*v0.x + v0.y*v0.y + v0.z*v0.z + v0.w*v0.w
            + v1.x*v1.x + v1.y*v1.y + v1.z*v1.z + v1.w*v1.w;
    #pragma unroll
    for (int off = 32; off; off >>= 1) s += __shfl_xor(s, off);
    if (lane == 0) cbsq[row] = s;
  }
  if (blockIdx.x == 0 && threadIdx.x < (int)Q) loss_out[threadIdx.x] = 0.f;
}

#define BARRIER  asm volatile("s_barrier" ::: "memory")
#define LGKM0    asm volatile("s_waitcnt lgkmcnt(0)" ::: "memory")
#define SCHEDB   __builtin_amdgcn_sched_barrier(0)

// ---------------- fused stage: 4-phase interleaved MFMA argmin + rotate ----------------
// Grid 256 x 512 threads (1 block/CU, 8 waves 2x4, wave tile 64x64, acc 4x4). Block owns
// 128 rows; 64 K-steps (4 col-tiles x 16 BK=32). 3 LDS buffers. Per K-step = 4 phases,
// each {ds_read subtile | 2 stage loads | s_barrier | lgkmcnt(0) | setprio(1) | 12 MFMA
// quadrant | setprio(0) | s_barrier}; counted vmcnt(6) once per K-step (R8, verified).
// EPILOGUE v2 (this round): zq and qq are NOT recomputed elementwise -- they are
// recovered from the GEMM: qq = cbsq[c] (exact), zq = (cbsq[c] - inv_fkey(d2key))/2
// (the dot as the MFMA computed it, ~1e-4 abs). Shuffle chain drops 18 -> 6 ops/row
// (zz alone); row loop unrolled x2 so loads pipeline under the reduce chain.
__global__ __launch_bounds__(512, 2) void stage_kernel(
    const float* __restrict__ x, const float* __restrict__ cbq_f32,
    unsigned short* __restrict__ Rhi, unsigned short* __restrict__ Rlo,
    const unsigned short* __restrict__ Chi, const unsigned short* __restrict__ Clo,
    const float* __restrict__ cq_base, float* __restrict__ qout,
    float* __restrict__ idx_out, float* __restrict__ loss_out,
    int qi, int last) {
  __shared__ unsigned short As[3][2][128 * 32];    // [buf][hi/lo] 48 KB
  __shared__ unsigned short Bs[3][2][256 * 32];    // [buf][hi/lo] 96 KB
  __shared__ unsigned long long bestLDS[4][128];   // 4 KB
  __shared__ float ls[8];

  const int tid = threadIdx.x;
  const int lane = tid & 63;
  const int w = tid >> 6;              // 0..7
  const int wr = w >> 2, wc = w & 3;   // wave grid 2 (rows) x 4 (cols)
  const int row0 = blockIdx.x * 128;

  // staging: lane -> (row-in-chunk rw, LDS slot oq); global octet pre-swizzled
  const int rw = lane >> 2, oq = lane & 3;
  const int o_sw = (oq - rw - (rw >> 2)) & 3;
  // fragment read: lane -> (row m, k-octet g); swizzled slot
  const int m = lane & 15, g = lane >> 4;
  const int f_sw8 = ((g + m + (m >> 2)) & 3) * 8;

  // global staging base pointers (per-lane)
  const unsigned short* pAhi = Rhi + (size_t)(row0 + w * 16 + rw) * 512 + o_sw * 8;
  const unsigned short* pAlo = Rlo + (size_t)(row0 + w * 16 + rw) * 512 + o_sw * 8;
  const unsigned short* pBhi = Chi + (size_t)(w * 32 + rw) * 512 + o_sw * 8;
  const unsigned short* pBlo = Clo + (size_t)(w * 32 + rw) * 512 + o_sw * 8;

  // LDS read base addresses (byte offsets), buf 0
  unsigned aA = lds_off(&As[0][0][(wr * 64 + m) * 32 + f_sw8]);
  unsigned aB = lds_off(&Bs[0][0][(wc * 64 + m) * 32 + f_sw8]);

  unsigned long long best[4][4];
  #pragma unroll
  for (int mi = 0; mi < 4; mi++)
    #pragma unroll
    for (int r = 0; r < 4; r++) best[mi][r] = ~0ull;

  // staging split into 3 parts of 2 global_load_lds each (spread across phases)
  auto stageA = [&](int buf, int t) {
    const size_t ko = (size_t)((t & 15) * 32);
    __builtin_amdgcn_global_load_lds(AS1(pAhi + ko), AS3(&As[buf][0][w * 512]), 16, 0, 0);
    __builtin_amdgcn_global_load_lds(AS1(pAlo + ko), AS3(&As[buf][1][w * 512]), 16, 0, 0);
  };
  auto stageB1 = [&](int buf, int t) {
    const size_t ko = (size_t)((t & 15) * 32);
    const size_t cof = (size_t)((t >> 4) * 256) * 512;
    unsigned short* dBh = &Bs[buf][0][w * 1024];
    __builtin_amdgcn_global_load_lds(AS1(pBhi + cof + ko), AS3(dBh), 16, 0, 0);
    __builtin_amdgcn_global_load_lds(AS1(pBhi + cof + ko + 8192), AS3(dBh + 512), 16, 0, 0);
  };
  auto stageB2 = [&](int buf, int t) {
    const size_t ko = (size_t)((t & 15) * 32);
    const size_t cof = (size_t)((t >> 4) * 256) * 512;
    unsigned short* dBl = &Bs[buf][1][w * 1024];
    __builtin_amdgcn_global_load_lds(AS1(pBlo + cof + ko), AS3(dBl), 16, 0, 0);
    __builtin_amdgcn_global_load_lds(AS1(pBlo + cof + ko + 8192), AS3(dBl + 512), 16, 0, 0);
  };

  // ---- prologue ----
  // cq via asm loads (kept out of compiler vmcnt accounting), retired immediately
  float cq[4][4];
  {
    unsigned long long cqp = (unsigned long long)(cq_base + wc * 64 + m);
    cq[0][0] = gload_f32<0>(cqp);    cq[0][1] = gload_f32<64>(cqp);
    cq[0][2] = gload_f32<128>(cqp);  cq[0][3] = gload_f32<192>(cqp);
    cq[1][0] = gload_f32<1024>(cqp); cq[1][1] = gload_f32<1088>(cqp);
    cq[1][2] = gload_f32<1152>(cqp); cq[1][3] = gload_f32<1216>(cqp);
    cq[2][0] = gload_f32<2048>(cqp); cq[2][1] = gload_f32<2112>(cqp);
    cq[2][2] = gload_f32<2176>(cqp); cq[2][3] = gload_f32<2240>(cqp);
    cq[3][0] = gload_f32<3072>(cqp); cq[3][1] = gload_f32<3136>(cqp);
    cq[3][2] = gload_f32<3200>(cqp); cq[3][3] = gload_f32<3264>(cqp);
    asm volatile("s_waitcnt vmcnt(0)" ::: "memory");
  }

  // fill buffers 0,1 with tiles 0,1
  stageA(0, 0); stageB1(0, 0); stageB2(0, 0);
  stageA(1, 1); stageB1(1, 1); stageB2(1, 1);
  asm volatile("s_waitcnt vmcnt(6)" ::: "memory");  // tile 0 landed; tile 1 in flight
  BARRIER;
  SCHEDB;

  bf16x8 ah[4], al[4], bh[4], bl[4];
  f32x4 acc[4][4];
  int bn = 0;   // buf holding tile t (reads)
  int bst = 2;  // buf target for stage(t+2)

  for (int t = 0; t < 64; ++t) {
    const int kk = t & 15;

    // ================= P0: read A01+B01, stage A(t+2), MFMA Q0 = A01*B01 ========
    ah[0] = ds_read128<0>(aA);     ah[1] = ds_read128<1024>(aA);
    al[0] = ds_read128<8192>(aA);  al[1] = ds_read128<9216>(aA);
    bh[0] = ds_read128<0>(aB);     bh[1] = ds_read128<1024>(aB);
    bl[0] = ds_read128<16384>(aB); bl[1] = ds_read128<17408>(aB);
    if (t < 62) stageA(bst, t + 2);
    if (kk == 0) {
      #pragma unroll
      for (int mi = 0; mi < 4; mi++)
        #pragma unroll
        for (int ni = 0; ni < 4; ni++)
          acc[mi][ni] = (f32x4){0.f, 0.f, 0.f, 0.f};
    }
    BARRIER; LGKM0; SCHEDB;
    __builtin_amdgcn_s_setprio(1);
    #pragma unroll
    for (int mi = 0; mi < 2; mi++)
      #pragma unroll
      for (int ni = 0; ni < 2; ni++)
        acc[mi][ni] = __builtin_amdgcn_mfma_f32_16x16x32_bf16(ah[mi], bh[ni], acc[mi][ni], 0, 0, 0);
    #pragma unroll
    for (int mi = 0; mi < 2; mi++)
      #pragma unroll
      for (int ni = 0; ni < 2; ni++)
        acc[mi][ni] = __builtin_amdgcn_mfma_f32_16x16x32_bf16(ah[mi], bl[ni], acc[mi][ni], 0, 0, 0);
    #pragma unroll
    for (int mi = 0; mi < 2; mi++)
      #pragma unroll
      for (int ni = 0; ni < 2; ni++)
        acc[mi][ni] = __builtin_amdgcn_mfma_f32_16x16x32_bf16(al[mi], bh[ni], acc[mi][ni], 0, 0, 0);
    __builtin_amdgcn_s_setprio(0);
    BARRIER; SCHEDB;

    // ================= P1: read B23, stage Bhi(t+2), MFMA Q1 = A01*B23 ==========
    bh[2] = ds_read128<2048>(aB);  bh[3] = ds_read128<3072>(aB);
    bl[2] = ds_read128<18432>(aB); bl[3] = ds_read128<19456>(aB);
    if (t < 62) stageB1(bst, t + 2);
    BARRIER; LGKM0; SCHEDB;
    __builtin_amdgcn_s_setprio(1);
    #pragma unroll
    for (int mi = 0; mi < 2; mi++)
      #pragma unroll
      for (int ni = 2; ni < 4; ni++)
        acc[mi][ni] = __builtin_amdgcn_mfma_f32_16x16x32_bf16(ah[mi], bh[ni], acc[mi][ni], 0, 0, 0);
    #pragma unroll
    for (int mi = 0; mi < 2; mi++)
      #pragma unroll
      for (int ni = 2; ni < 4; ni++)
        acc[mi][ni] = __builtin_amdgcn_mfma_f32_16x16x32_bf16(ah[mi], bl[ni], acc[mi][ni], 0, 0, 0);
    #pragma unroll
    for (int mi = 0; mi < 2; mi++)
      #pragma unroll
      for (int ni = 2; ni < 4; ni++)
        acc[mi][ni] = __builtin_amdgcn_mfma_f32_16x16x32_bf16(al[mi], bh[ni], acc[mi][ni], 0, 0, 0);
    __builtin_amdgcn_s_setprio(0);
    BARRIER; SCHEDB;

    // ================= P2: read A23, stage Blo(t+2), MFMA Q2 = A23*B23 ==========
    ah[2] = ds_read128<2048>(aA);  ah[3] = ds_read128<3072>(aA);
    al[2] = ds_read128<10240>(aA); al[3] = ds_read128<11264>(aA);
    if (t < 62) stageB2(bst, t + 2);
    BARRIER; LGKM0; SCHEDB;
    __builtin_amdgcn_s_setprio(1);
    #pragma unroll
    for (int mi = 2; mi < 4; mi++)
      #pragma unroll
      for (int ni = 2; ni < 4; ni++)
        acc[mi][ni] = __builtin_amdgcn_mfma_f32_16x16x32_bf16(ah[mi], bh[ni], acc[mi][ni], 0, 0, 0);
    #pragma unroll
    for (int mi = 2; mi < 4; mi++)
      #pragma unroll
      for (int ni = 2; ni < 4; ni++)
        acc[mi][ni] = __builtin_amdgcn_mfma_f32_16x16x32_bf16(ah[mi], bl[ni], acc[mi][ni], 0, 0, 0);
    #pragma unroll
    for (int mi = 2; mi < 4; mi++)
      #pragma unroll
      for (int ni = 2; ni < 4; ni++)
        acc[mi][ni] = __builtin_amdgcn_mfma_f32_16x16x32_bf16(al[mi], bh[ni], acc[mi][ni], 0, 0, 0);
    __builtin_amdgcn_s_setprio(0);
    BARRIER; SCHEDB;

    // ================= P3: MFMA Q3 = A23*B01, fold, counted vmcnt ===============
    __builtin_amdgcn_s_setprio(1);
    #pragma unroll
    for (int mi = 2; mi < 4; mi++)
      #pragma unroll
      for (int ni = 0; ni < 2; ni++)
        acc[mi][ni] = __builtin_amdgcn_mfma_f32_16x16x32_bf16(ah[mi], bh[ni], acc[mi][ni], 0, 0, 0);
    #pragma unroll
    for (int mi = 2; mi < 4; mi++)
      #pragma unroll
      for (int ni = 0; ni < 2; ni++)
        acc[mi][ni] = __builtin_amdgcn_mfma_f32_16x16x32_bf16(ah[mi], bl[ni], acc[mi][ni], 0, 0, 0);
    #pragma unroll
    for (int mi = 2; mi < 4; mi++)
      #pragma unroll
      for (int ni = 0; ni < 2; ni++)
        acc[mi][ni] = __builtin_amdgcn_mfma_f32_16x16x32_bf16(al[mi], bh[ni], acc[mi][ni], 0, 0, 0);
    __builtin_amdgcn_s_setprio(0);
    if (kk == 15) { // per-lane fold (cross-lane reduce deferred to after loop)
      const int ct_ = t >> 4;
      const unsigned colb = ct_ * 256 + wc * 64 + m;
      #pragma unroll
      for (int mi = 0; mi < 4; mi++)
        #pragma unroll
        for (int r = 0; r < 4; r++) {
          #pragma unroll
          for (int ni = 0; ni < 4; ni++) {
            float d2 = fmaf(-2.f, acc[mi][ni][r], cq[ct_][ni]);
            unsigned long long p =
                (((unsigned long long)fkey(d2)) << 32) | (colb + ni * 16);
            if (p < best[mi][r]) best[mi][r] = p;
          }
        }
    }
    // counted wait: tile t+1 (issued a full iter ago) forced; t+2 stays in flight
    if (t < 62) asm volatile("s_waitcnt vmcnt(6)" ::: "memory");
    else        asm volatile("s_waitcnt vmcnt(0)" ::: "memory");
    BARRIER; SCHEDB;

    // advance read buffer to tile t+1; advance stage target
    const int s_ = (bn == 2) ? -2 : 1;
    aA += s_ * 16384; aB += s_ * 32768;
    bn = (bn == 2) ? 0 : bn + 1;
    bst = (bst == 2) ? 0 : bst + 1;
  }

  // deferred cross-lane argmin reduce (over the 16 cols in each fragment)
  #pragma unroll
  for (int mi = 0; mi < 4; mi++)
    #pragma unroll
    for (int r = 0; r < 4; r++) {
      unsigned long long mn = best[mi][r];
      #pragma unroll
      for (int off = 1; off < 16; off <<= 1) {
        unsigned long long o = shfl_xor_u64(mn, off);
        if (o < mn) mn = o;
      }
      best[mi][r] = mn;
    }

  // publish per-row argmin quarters (wc = 0..3) to LDS
  if (m == 0) {
    #pragma unroll
    for (int mi = 0; mi < 4; mi++)
      #pragma unroll
      for (int r = 0; r < 4; r++)
        bestLDS[wc][wr * 64 + mi * 16 + g * 4 + r] = best[mi][r];
  }
  __syncthreads();

  // ---------------- rotate epilogue v2: 16 rows per wave ----------------
  // zq/qq recovered from the GEMM (d2-key inversion + cbsq); only zz is reduced
  // elementwise (single-value 6-level shuffle chain). Unroll 2 pipelines the loads.
  float lossacc = 0.f;
  #pragma unroll 2
  for (int rr = 0; rr < 16; rr++) {
    const int row128 = w * 16 + rr;
    unsigned long long mn = bestLDS[0][row128];
    #pragma unroll
    for (int q2 = 1; q2 < 4; q2++) {
      unsigned long long o = bestLDS[q2][row128];
      if (o < mn) mn = o;
    }
    const int c = (int)(mn & 0xffffffffu);
    const int row = row0 + row128;
    if (lane == 0) idx_out[(size_t)row * 8 + qi] = (float)c;

    // scalars recovered from the GEMM fold (no elementwise recompute):
    const float qq = cq_base[c];                       // ||q||^2, fp32-exact
    const float d2b = inv_fkey((unsigned)(mn >> 32));  // d2 = qq - 2*(r.q)
    const float zq = (qq - d2b) * 0.5f;                // r.q as the MFMA computed it

    const size_t base = (size_t)row * 512 + lane * 8;
    ushort8 h = *(const ushort8*)(Rhi + base);
    ushort8 l = *(const ushort8*)(Rlo + base);
    const float* qrow = cbq_f32 + (size_t)c * 512 + lane * 8;
    float4 q0 = *(const float4*)qrow;
    float4 q1 = *(const float4*)(qrow + 4);
    float z[8], q[8] = {q0.x, q0.y, q0.z, q0.w, q1.x, q1.y, q1.z, q1.w};
    #pragma unroll
    for (int j = 0; j < 8; j++) z[j] = bf2f(h[j]) + bf2f(l[j]);

    float zz = 0.f;
    #pragma unroll
    for (int j = 0; j < 8; j++) zz = fmaf(z[j], z[j], zz);
    #pragma unroll
    for (int off = 32; off; off >>= 1) zz += __shfl_xor(zz, off);

    float nz = sqrtf(zz), nq = sqrtf(qq);
    float inz = 1.f / (nz + EPS), inq = 1.f / (nq + EPS);
    float ns  = sqrtf(zz*inz*inz + 2.f*zq*inz*inq + qq*inq*inq);
    float ins = 1.f / ns;
    float zw  = (zz*inz + zq*inq) * ins;
    float zzn = zz * inz;
    float scale = nq * inz;
    float az = scale * (1.f - 2.f * zw * ins * inz);
    float aq = scale * (2.f * zzn - 2.f * zw * ins) * inq;

    if (!last) {
      #pragma unroll
      for (int j = 0; j < 8; j++) {
        float r = z[j] - (az * z[j] + aq * q[j]);
        unsigned short hh = f2bf(r);
        h[j] = hh;
        l[j] = f2bf(r - bf2f(hh));
      }
      *(ushort8*)(Rhi + base) = h;
      *(ushort8*)(Rlo + base) = l;
    } else {
      float4 x0 = *(const float4*)(x + base);
      float4 x1 = *(const float4*)(x + base + 4);
      float xv[8] = {x0.x, x0.y, x0.z, x0.w, x1.x, x1.y, x1.z, x1.w};
      float o[8];
      #pragma unroll
      for (int j = 0; j < 8; j++) {
        float r = z[j] - (az * z[j] + aq * q[j]);
        o[j] = xv[j] - r;
      }
      *(float4*)(qout + base)     = (float4){o[0], o[1], o[2], o[3]};
      *(float4*)(qout + base + 4) = (float4){o[4], o[5], o[6], o[7]};
    }
    lossacc += (zz - 2.f * zq + qq);
  }
  if (lane == 0) ls[w] = lossacc;
  __syncthreads();
  if (tid == 0)
    atomicAdd(loss_out + qi, (ls[0] + ls[1] + ls[2] + ls[3] +
                              ls[4] + ls[5] + ls[6] + ls[7]) *
                             (1.f / (32768.f * 512.f)));
}

extern "C" void kernel_launch(void* const* d_in, const int* in_sizes, int n_in,
                              void* d_out, int out_size, void* d_ws, size_t ws_size,
                              hipStream_t stream) {
  const float* x   = (const float*)d_in[0];   // [16, 2048, 512]
  const float* cbs = (const float*)d_in[1];   // [8, 1024, 512]
  float* out = (float*)d_out;
  const size_t M = 32768, D = 512, Q = 8, C = 1024;
  float* qout     = out;                 // [M, D]
  float* idx_out  = out + M * D;         // [M, Q] (as float)
  float* loss_out = idx_out + M * Q;     // [Q]

  // ws: Rhi 32M | Rlo 32M | CBhi 8M | CBlo 8M | cbsq 32K
  unsigned short* Rhi  = (unsigned short*)d_ws;
  unsigned short* Rlo  = Rhi + M * D;
  unsigned short* CBhi = Rlo + M * D;
  unsigned short* CBlo = CBhi + Q * C * D;
  float* cbsq = (float*)(CBlo + Q * C * D);

  prep_kernel<<<512, 256, 0, stream>>>(x, cbs, Rhi, Rlo, CBhi, CBlo, cbsq, loss_out);

  for (int qi = 0; qi < (int)Q; qi++) {
    stage_kernel<<<256, 512, 0, stream>>>(
        x, cbs + (size_t)qi * C * D, Rhi, Rlo,
        CBhi + (size_t)qi * C * D, CBlo + (size_t)qi * C * D,
        cbsq + qi * C, qout, idx_out, loss_out, qi, qi == (int)Q - 1 ? 1 : 0);
  }
}

// Round 10
// 1089.103 us; speedup vs baseline: 1.0778x; 1.0778x over previous
//
#include <hip/hip_runtime.h>

#define EPS 1e-6f

typedef __attribute__((ext_vector_type(8))) short bf16x8;
typedef __attribute__((ext_vector_type(4))) float f32x4;
typedef __attribute__((ext_vector_type(8))) unsigned short ushort8;

#define AS1(p) ((const __attribute__((address_space(1))) void*)(p))
#define AS3(p) ((__attribute__((address_space(3))) void*)(p))

__device__ inline unsigned int fkey(float f) {
  unsigned int u = __float_as_uint(f);
  return (u & 0x80000000u) ? ~u : (u | 0x80000000u);
}
// inverse of fkey: recover the exact fp32 bits
__device__ inline float inv_fkey(unsigned int k) {
  unsigned int u = (k & 0x80000000u) ? (k & 0x7fffffffu) : ~k;
  return __uint_as_float(u);
}

__device__ inline unsigned long long shfl_xor_u64(unsigned long long v, int mask) {
  unsigned int lo = (unsigned int)(v & 0xffffffffull);
  unsigned int hi = (unsigned int)(v >> 32);
  lo = (unsigned int)__shfl_xor((int)lo, mask);
  hi = (unsigned int)__shfl_xor((int)hi, mask);
  return (((unsigned long long)hi) << 32) | lo;
}

__device__ inline unsigned short f2bf(float f) {  // RNE fp32 -> bf16
  unsigned int u = __float_as_uint(f);
  u += 0x7fffu + ((u >> 16) & 1u);
  return (unsigned short)(u >> 16);
}
__device__ inline float bf2f(unsigned short h) {
  return __uint_as_float(((unsigned int)h) << 16);
}

// LDS byte-offset of a __shared__ address (AS3 pointers are 32-bit)
__device__ inline unsigned lds_off(const void* p) {
  return (unsigned)(unsigned long long)(__attribute__((address_space(3))) const void*)p;
}

// asm ds_read_b128 with immediate offset: compiler-untracked (we control lgkmcnt)
template<int OFF>
__device__ inline bf16x8 ds_read128(unsigned addr) {
  bf16x8 r;
  asm volatile("ds_read_b128 %0, %1 offset:%2" : "=v"(r) : "v"(addr), "i"(OFF));
  return r;
}

// asm global f32 load with immediate offset (keeps compiler vmcnt accounting clean)
template<int OFF>
__device__ inline float gload_f32(unsigned long long a) {
  float r;
  asm volatile("global_load_dword %0, %1, off offset:%2" : "=v"(r) : "v"(a), "i"(OFF));
  return r;
}

// ---------------- prep: splits + codebook norms + loss zero (one kernel) ----------------
__global__ __launch_bounds__(256) void prep_kernel(
    const float* __restrict__ x, const float* __restrict__ cbs,
    unsigned short* __restrict__ Rhi, unsigned short* __restrict__ Rlo,
    unsigned short* __restrict__ CBhi, unsigned short* __restrict__ CBlo,
    float* __restrict__ cbsq, float* __restrict__ loss_out) {
  constexpr size_t M = 32768, D = 512, C = 1024, Q = 8;
  const size_t nthreads = (size_t)gridDim.x * 256;
  const size_t gtid = (size_t)blockIdx.x * 256 + threadIdx.x;
  const int lane = threadIdx.x & 63;
  const int w = threadIdx.x >> 6;

  for (size_t i = gtid; i < M * D / 8; i += nthreads) {
    size_t off = i * 8;
    float4 v0 = *(const float4*)(x + off);
    float4 v1 = *(const float4*)(x + off + 4);
    float v[8] = {v0.x, v0.y, v0.z, v0.w, v1.x, v1.y, v1.z, v1.w};
    ushort8 h, l;
    #pragma unroll
    for (int j = 0; j < 8; j++) {
      unsigned short hh = f2bf(v[j]);
      h[j] = hh;
      l[j] = f2bf(v[j] - bf2f(hh));
    }
    *(ushort8*)(Rhi + off) = h;
    *(ushort8*)(Rlo + off) = l;
  }
  for (size_t i = gtid; i < Q * C * D / 8; i += nthreads) {
    size_t off = i * 8;
    float4 v0 = *(const float4*)(cbs + off);
    float4 v1 = *(const float4*)(cbs + off + 4);
    float v[8] = {v0.x, v0.y, v0.z, v0.w, v1.x, v1.y, v1.z, v1.w};
    ushort8 h, l;
    #pragma unroll
    for (int j = 0; j < 8; j++) {
      unsigned short hh = f2bf(v[j]);
      h[j] = hh;
      l[j] = f2bf(v[j] - bf2f(hh));
    }
    *(ushort8*)(CBhi + off) = h;
    *(ushort8*)(CBlo + off) = l;
  }
  for (int row = blockIdx.x * 4 + w; row < (int)(Q * C); row += gridDim.x * 4) {
    const float4* p = (const float4*)(cbs + (size_t)row * 512);
    float4 v0 = p[lane];
    float4 v1 = p[lane + 64];
    float s = v0.x*v0.x + v0.y*v0.y + v0.z*v0.z + v0.w*v0.w
            + v1.x*v1.x + v1.y*v1.y + v1.z*v1.z + v1.w*v1.w;
    #pragma unroll
    for (int off = 32; off; off >>= 1) s += __shfl_xor(s, off);
    if (lane == 0) cbsq[row] = s;
  }
  if (blockIdx.x == 0 && threadIdx.x < (int)Q) loss_out[threadIdx.x] = 0.f;
}

#define BARRIER  asm volatile("s_barrier" ::: "memory")
#define LGKM0    asm volatile("s_waitcnt lgkmcnt(0)" ::: "memory")
#define SCHEDB   __builtin_amdgcn_sched_barrier(0)

// ---------------- fused ALL-STAGES kernel: 8x (4-phase MFMA argmin + rotate) ------------
// KEY CHANGE (R10): the RVQ recursion is ROW-LOCAL -- block b's stage-qi GEMM reads
// exactly the residual rows block b's stage-(qi-1) epilogue wrote, and the codebook
// switch is a pointer offset. So all 8 stages fuse into ONE persistent kernel:
// grid 256 x 512 (1 block/CU), for(qi=0..7){ stage body }. Eliminates 7 device-wide
// barriers (launches), 7x pipeline fill/drain, and lets blocks desynchronize across
// stages (tail absorption); the epilogue->restage residual round-trip is L2-warm.
// Stage body is byte-identical to the verified R8/R9 kernel: 4-phase interleave,
// 3 LDS buffers, counted vmcnt(6), setprio, d2-recovery epilogue.
// Cross-stage ordering: per-stage cq loads end in vmcnt(0), which also retires the
// previous epilogue's Rhi/Rlo stores; the staging wave re-reads exactly the rows IT
// wrote (same-wave VMEM dependency), so vmcnt(0) suffices. __syncthreads() at stage
// top makes LDS buffer reuse safe.
__global__ __launch_bounds__(512, 2) void stage_kernel(
    const float* __restrict__ x, const float* __restrict__ cbs,
    unsigned short* __restrict__ Rhi, unsigned short* __restrict__ Rlo,
    const unsigned short* __restrict__ CBhi, const unsigned short* __restrict__ CBlo,
    const float* __restrict__ cbsq, float* __restrict__ qout,
    float* __restrict__ idx_out, float* __restrict__ loss_out) {
  __shared__ unsigned short As[3][2][128 * 32];    // [buf][hi/lo] 48 KB
  __shared__ unsigned short Bs[3][2][256 * 32];    // [buf][hi/lo] 96 KB
  __shared__ unsigned long long bestLDS[4][128];   // 4 KB
  __shared__ float ls[8];

  const int tid = threadIdx.x;
  const int lane = tid & 63;
  const int w = tid >> 6;              // 0..7
  const int wr = w >> 2, wc = w & 3;   // wave grid 2 (rows) x 4 (cols)
  const int row0 = blockIdx.x * 128;

  // staging: lane -> (row-in-chunk rw, LDS slot oq); global octet pre-swizzled
  const int rw = lane >> 2, oq = lane & 3;
  const int o_sw = (oq - rw - (rw >> 2)) & 3;
  // fragment read: lane -> (row m, k-octet g); swizzled slot
  const int m = lane & 15, g = lane >> 4;
  const int f_sw8 = ((g + m + (m >> 2)) & 3) * 8;

  // global staging base pointers (per-lane); A constant across stages
  const unsigned short* pAhi = Rhi + (size_t)(row0 + w * 16 + rw) * 512 + o_sw * 8;
  const unsigned short* pAlo = Rlo + (size_t)(row0 + w * 16 + rw) * 512 + o_sw * 8;

  for (int qi = 0; qi < 8; ++qi) {
    const int last = (qi == 7);
    const size_t cbo = (size_t)qi * 524288;  // C*D
    const unsigned short* pBhi = CBhi + cbo + (size_t)(w * 32 + rw) * 512 + o_sw * 8;
    const unsigned short* pBlo = CBlo + cbo + (size_t)(w * 32 + rw) * 512 + o_sw * 8;
    const float* cq_base = cbsq + (qi << 10);
    const float* cbq_f32 = cbs + cbo;

    // LDS read base addresses (byte offsets), buf 0
    unsigned aA = lds_off(&As[0][0][(wr * 64 + m) * 32 + f_sw8]);
    unsigned aB = lds_off(&Bs[0][0][(wc * 64 + m) * 32 + f_sw8]);

    unsigned long long best[4][4];
    #pragma unroll
    for (int mi = 0; mi < 4; mi++)
      #pragma unroll
      for (int r = 0; r < 4; r++) best[mi][r] = ~0ull;

    // staging split into 3 parts of 2 global_load_lds each (spread across phases)
    auto stageA = [&](int buf, int t) {
      const size_t ko = (size_t)((t & 15) * 32);
      __builtin_amdgcn_global_load_lds(AS1(pAhi + ko), AS3(&As[buf][0][w * 512]), 16, 0, 0);
      __builtin_amdgcn_global_load_lds(AS1(pAlo + ko), AS3(&As[buf][1][w * 512]), 16, 0, 0);
    };
    auto stageB1 = [&](int buf, int t) {
      const size_t ko = (size_t)((t & 15) * 32);
      const size_t cof = (size_t)((t >> 4) * 256) * 512;
      unsigned short* dBh = &Bs[buf][0][w * 1024];
      __builtin_amdgcn_global_load_lds(AS1(pBhi + cof + ko), AS3(dBh), 16, 0, 0);
      __builtin_amdgcn_global_load_lds(AS1(pBhi + cof + ko + 8192), AS3(dBh + 512), 16, 0, 0);
    };
    auto stageB2 = [&](int buf, int t) {
      const size_t ko = (size_t)((t & 15) * 32);
      const size_t cof = (size_t)((t >> 4) * 256) * 512;
      unsigned short* dBl = &Bs[buf][1][w * 1024];
      __builtin_amdgcn_global_load_lds(AS1(pBlo + cof + ko), AS3(dBl), 16, 0, 0);
      __builtin_amdgcn_global_load_lds(AS1(pBlo + cof + ko + 8192), AS3(dBl + 512), 16, 0, 0);
    };

    // stage top: all waves done with previous stage (LDS reuse + ls/bestLDS safe)
    __syncthreads();

    // cq via asm loads; the vmcnt(0) also retires the previous epilogue's stores
    float cq[4][4];
    {
      unsigned long long cqp = (unsigned long long)(cq_base + wc * 64 + m);
      cq[0][0] = gload_f32<0>(cqp);    cq[0][1] = gload_f32<64>(cqp);
      cq[0][2] = gload_f32<128>(cqp);  cq[0][3] = gload_f32<192>(cqp);
      cq[1][0] = gload_f32<1024>(cqp); cq[1][1] = gload_f32<1088>(cqp);
      cq[1][2] = gload_f32<1152>(cqp); cq[1][3] = gload_f32<1216>(cqp);
      cq[2][0] = gload_f32<2048>(cqp); cq[2][1] = gload_f32<2112>(cqp);
      cq[2][2] = gload_f32<2176>(cqp); cq[2][3] = gload_f32<2240>(cqp);
      cq[3][0] = gload_f32<3072>(cqp); cq[3][1] = gload_f32<3136>(cqp);
      cq[3][2] = gload_f32<3200>(cqp); cq[3][3] = gload_f32<3264>(cqp);
      asm volatile("s_waitcnt vmcnt(0)" ::: "memory");
    }

    // fill buffers 0,1 with tiles 0,1
    stageA(0, 0); stageB1(0, 0); stageB2(0, 0);
    stageA(1, 1); stageB1(1, 1); stageB2(1, 1);
    asm volatile("s_waitcnt vmcnt(6)" ::: "memory");  // tile 0 landed; tile 1 in flight
    BARRIER;
    SCHEDB;

    bf16x8 ah[4], al[4], bh[4], bl[4];
    f32x4 acc[4][4];
    int bn = 0;   // buf holding tile t (reads)
    int bst = 2;  // buf target for stage(t+2)

    for (int t = 0; t < 64; ++t) {
      const int kk = t & 15;

      // ================= P0: read A01+B01, stage A(t+2), MFMA Q0 = A01*B01 ========
      ah[0] = ds_read128<0>(aA);     ah[1] = ds_read128<1024>(aA);
      al[0] = ds_read128<8192>(aA);  al[1] = ds_read128<9216>(aA);
      bh[0] = ds_read128<0>(aB);     bh[1] = ds_read128<1024>(aB);
      bl[0] = ds_read128<16384>(aB); bl[1] = ds_read128<17408>(aB);
      if (t < 62) stageA(bst, t + 2);
      if (kk == 0) {
        #pragma unroll
        for (int mi = 0; mi < 4; mi++)
          #pragma unroll
          for (int ni = 0; ni < 4; ni++)
            acc[mi][ni] = (f32x4){0.f, 0.f, 0.f, 0.f};
      }
      BARRIER; LGKM0; SCHEDB;
      __builtin_amdgcn_s_setprio(1);
      #pragma unroll
      for (int mi = 0; mi < 2; mi++)
        #pragma unroll
        for (int ni = 0; ni < 2; ni++)
          acc[mi][ni] = __builtin_amdgcn_mfma_f32_16x16x32_bf16(ah[mi], bh[ni], acc[mi][ni], 0, 0, 0);
      #pragma unroll
      for (int mi = 0; mi < 2; mi++)
        #pragma unroll
        for (int ni = 0; ni < 2; ni++)
          acc[mi][ni] = __builtin_amdgcn_mfma_f32_16x16x32_bf16(ah[mi], bl[ni], acc[mi][ni], 0, 0, 0);
      #pragma unroll
      for (int mi = 0; mi < 2; mi++)
        #pragma unroll
        for (int ni = 0; ni < 2; ni++)
          acc[mi][ni] = __builtin_amdgcn_mfma_f32_16x16x32_bf16(al[mi], bh[ni], acc[mi][ni], 0, 0, 0);
      __builtin_amdgcn_s_setprio(0);
      BARRIER; SCHEDB;

      // ================= P1: read B23, stage Bhi(t+2), MFMA Q1 = A01*B23 ==========
      bh[2] = ds_read128<2048>(aB);  bh[3] = ds_read128<3072>(aB);
      bl[2] = ds_read128<18432>(aB); bl[3] = ds_read128<19456>(aB);
      if (t < 62) stageB1(bst, t + 2);
      BARRIER; LGKM0; SCHEDB;
      __builtin_amdgcn_s_setprio(1);
      #pragma unroll
      for (int mi = 0; mi < 2; mi++)
        #pragma unroll
        for (int ni = 2; ni < 4; ni++)
          acc[mi][ni] = __builtin_amdgcn_mfma_f32_16x16x32_bf16(ah[mi], bh[ni], acc[mi][ni], 0, 0, 0);
      #pragma unroll
      for (int mi = 0; mi < 2; mi++)
        #pragma unroll
        for (int ni = 2; ni < 4; ni++)
          acc[mi][ni] = __builtin_amdgcn_mfma_f32_16x16x32_bf16(ah[mi], bl[ni], acc[mi][ni], 0, 0, 0);
      #pragma unroll
      for (int mi = 0; mi < 2; mi++)
        #pragma unroll
        for (int ni = 2; ni < 4; ni++)
          acc[mi][ni] = __builtin_amdgcn_mfma_f32_16x16x32_bf16(al[mi], bh[ni], acc[mi][ni], 0, 0, 0);
      __builtin_amdgcn_s_setprio(0);
      BARRIER; SCHEDB;

      // ================= P2: read A23, stage Blo(t+2), MFMA Q2 = A23*B23 ==========
      ah[2] = ds_read128<2048>(aA);  ah[3] = ds_read128<3072>(aA);
      al[2] = ds_read128<10240>(aA); al[3] = ds_read128<11264>(aA);
      if (t < 62) stageB2(bst, t + 2);
      BARRIER; LGKM0; SCHEDB;
      __builtin_amdgcn_s_setprio(1);
      #pragma unroll
      for (int mi = 2; mi < 4; mi++)
        #pragma unroll
        for (int ni = 2; ni < 4; ni++)
          acc[mi][ni] = __builtin_amdgcn_mfma_f32_16x16x32_bf16(ah[mi], bh[ni], acc[mi][ni], 0, 0, 0);
      #pragma unroll
      for (int mi = 2; mi < 4; mi++)
        #pragma unroll
        for (int ni = 2; ni < 4; ni++)
          acc[mi][ni] = __builtin_amdgcn_mfma_f32_16x16x32_bf16(ah[mi], bl[ni], acc[mi][ni], 0, 0, 0);
      #pragma unroll
      for (int mi = 2; mi < 4; mi++)
        #pragma unroll
        for (int ni = 2; ni < 4; ni++)
          acc[mi][ni] = __builtin_amdgcn_mfma_f32_16x16x32_bf16(al[mi], bh[ni], acc[mi][ni], 0, 0, 0);
      __builtin_amdgcn_s_setprio(0);
      BARRIER; SCHEDB;

      // ================= P3: MFMA Q3 = A23*B01, fold, counted vmcnt ===============
      __builtin_amdgcn_s_setprio(1);
      #pragma unroll
      for (int mi = 2; mi < 4; mi++)
        #pragma unroll
        for (int ni = 0; ni < 2; ni++)
          acc[mi][ni] = __builtin_amdgcn_mfma_f32_16x16x32_bf16(ah[mi], bh[ni], acc[mi][ni], 0, 0, 0);
      #pragma unroll
      for (int mi = 2; mi < 4; mi++)
        #pragma unroll
        for (int ni = 0; ni < 2; ni++)
          acc[mi][ni] = __builtin_amdgcn_mfma_f32_16x16x32_bf16(ah[mi], bl[ni], acc[mi][ni], 0, 0, 0);
      #pragma unroll
      for (int mi = 2; mi < 4; mi++)
        #pragma unroll
        for (int ni = 0; ni < 2; ni++)
          acc[mi][ni] = __builtin_amdgcn_mfma_f32_16x16x32_bf16(al[mi], bh[ni], acc[mi][ni], 0, 0, 0);
      __builtin_amdgcn_s_setprio(0);
      if (kk == 15) { // per-lane fold (cross-lane reduce deferred to after loop)
        const int ct_ = t >> 4;
        const unsigned colb = ct_ * 256 + wc * 64 + m;
        #pragma unroll
        for (int mi = 0; mi < 4; mi++)
          #pragma unroll
          for (int r = 0; r < 4; r++) {
            #pragma unroll
            for (int ni = 0; ni < 4; ni++) {
              float d2 = fmaf(-2.f, acc[mi][ni][r], cq[ct_][ni]);
              unsigned long long p =
                  (((unsigned long long)fkey(d2)) << 32) | (colb + ni * 16);
              if (p < best[mi][r]) best[mi][r] = p;
            }
          }
      }
      // counted wait: tile t+1 (issued a full iter ago) forced; t+2 stays in flight
      if (t < 62) asm volatile("s_waitcnt vmcnt(6)" ::: "memory");
      else        asm volatile("s_waitcnt vmcnt(0)" ::: "memory");
      BARRIER; SCHEDB;

      // advance read buffer to tile t+1; advance stage target
      const int s_ = (bn == 2) ? -2 : 1;
      aA += s_ * 16384; aB += s_ * 32768;
      bn = (bn == 2) ? 0 : bn + 1;
      bst = (bst == 2) ? 0 : bst + 1;
    }

    // deferred cross-lane argmin reduce (over the 16 cols in each fragment)
    #pragma unroll
    for (int mi = 0; mi < 4; mi++)
      #pragma unroll
      for (int r = 0; r < 4; r++) {
        unsigned long long mn = best[mi][r];
        #pragma unroll
        for (int off = 1; off < 16; off <<= 1) {
          unsigned long long o = shfl_xor_u64(mn, off);
          if (o < mn) mn = o;
        }
        best[mi][r] = mn;
      }

    // publish per-row argmin quarters (wc = 0..3) to LDS
    if (m == 0) {
      #pragma unroll
      for (int mi = 0; mi < 4; mi++)
        #pragma unroll
        for (int r = 0; r < 4; r++)
          bestLDS[wc][wr * 64 + mi * 16 + g * 4 + r] = best[mi][r];
    }
    __syncthreads();

    // ---------------- rotate epilogue: 16 rows per wave ----------------
    float lossacc = 0.f;
    #pragma unroll 2
    for (int rr = 0; rr < 16; rr++) {
      const int row128 = w * 16 + rr;
      unsigned long long mn = bestLDS[0][row128];
      #pragma unroll
      for (int q2 = 1; q2 < 4; q2++) {
        unsigned long long o = bestLDS[q2][row128];
        if (o < mn) mn = o;
      }
      const int c = (int)(mn & 0xffffffffu);
      const int row = row0 + row128;
      if (lane == 0) idx_out[(size_t)row * 8 + qi] = (float)c;

      // scalars recovered from the GEMM fold (no elementwise recompute):
      const float qq = cq_base[c];                       // ||q||^2, fp32-exact
      const float d2b = inv_fkey((unsigned)(mn >> 32));  // d2 = qq - 2*(r.q)
      const float zq = (qq - d2b) * 0.5f;                // r.q as the MFMA computed it

      const size_t base = (size_t)row * 512 + lane * 8;
      ushort8 h = *(const ushort8*)(Rhi + base);
      ushort8 l = *(const ushort8*)(Rlo + base);
      const float* qrow = cbq_f32 + (size_t)c * 512 + lane * 8;
      float4 q0 = *(const float4*)qrow;
      float4 q1 = *(const float4*)(qrow + 4);
      float z[8], q[8] = {q0.x, q0.y, q0.z, q0.w, q1.x, q1.y, q1.z, q1.w};
      #pragma unroll
      for (int j = 0; j < 8; j++) z[j] = bf2f(h[j]) + bf2f(l[j]);

      float zz = 0.f;
      #pragma unroll
      for (int j = 0; j < 8; j++) zz = fmaf(z[j], z[j], zz);
      #pragma unroll
      for (int off = 32; off; off >>= 1) zz += __shfl_xor(zz, off);

      float nz = sqrtf(zz), nq = sqrtf(qq);
      float inz = 1.f / (nz + EPS), inq = 1.f / (nq + EPS);
      float ns  = sqrtf(zz*inz*inz + 2.f*zq*inz*inq + qq*inq*inq);
      float ins = 1.f / ns;
      float zw  = (zz*inz + zq*inq) * ins;
      float zzn = zz * inz;
      float scale = nq * inz;
      float az = scale * (1.f - 2.f * zw * ins * inz);
      float aq = scale * (2.f * zzn - 2.f * zw * ins) * inq;

      if (!last) {
        #pragma unroll
        for (int j = 0; j < 8; j++) {
          float r = z[j] - (az * z[j] + aq * q[j]);
          unsigned short hh = f2bf(r);
          h[j] = hh;
          l[j] = f2bf(r - bf2f(hh));
        }
        *(ushort8*)(Rhi + base) = h;
        *(ushort8*)(Rlo + base) = l;
      } else {
        float4 x0 = *(const float4*)(x + base);
        float4 x1 = *(const float4*)(x + base + 4);
        float xv[8] = {x0.x, x0.y, x0.z, x0.w, x1.x, x1.y, x1.z, x1.w};
        float o[8];
        #pragma unroll
        for (int j = 0; j < 8; j++) {
          float r = z[j] - (az * z[j] + aq * q[j]);
          o[j] = xv[j] - r;
        }
        *(float4*)(qout + base)     = (float4){o[0], o[1], o[2], o[3]};
        *(float4*)(qout + base + 4) = (float4){o[4], o[5], o[6], o[7]};
      }
      lossacc += (zz - 2.f * zq + qq);
    }
    if (lane == 0) ls[w] = lossacc;
    __syncthreads();
    if (tid == 0)
      atomicAdd(loss_out + qi, (ls[0] + ls[1] + ls[2] + ls[3] +
                                ls[4] + ls[5] + ls[6] + ls[7]) *
                               (1.f / (32768.f * 512.f)));
  }
}

extern "C" void kernel_launch(void* const* d_in, const int* in_sizes, int n_in,
                              void* d_out, int out_size, void* d_ws, size_t ws_size,
                              hipStream_t stream) {
  const float* x   = (const float*)d_in[0];   // [16, 2048, 512]
  const float* cbs = (const float*)d_in[1];   // [8, 1024, 512]
  float* out = (float*)d_out;
  const size_t M = 32768, D = 512, Q = 8, C = 1024;
  float* qout     = out;                 // [M, D]
  float* idx_out  = out + M * D;         // [M, Q] (as float)
  float* loss_out = idx_out + M * Q;     // [Q]

  // ws: Rhi 32M | Rlo 32M | CBhi 8M | CBlo 8M | cbsq 32K
  unsigned short* Rhi  = (unsigned short*)d_ws;
  unsigned short* Rlo  = Rhi + M * D;
  unsigned short* CBhi = Rlo + M * D;
  unsigned short* CBlo = CBhi + Q * C * D;
  float* cbsq = (float*)(CBlo + Q * C * D);

  prep_kernel<<<512, 256, 0, stream>>>(x, cbs, Rhi, Rlo, CBhi, CBlo, cbsq, loss_out);

  stage_kernel<<<256, 512, 0, stream>>>(
      x, cbs, Rhi, Rlo, CBhi, CBlo, cbsq, qout, idx_out, loss_out);
}

// Round 11
// 981.909 us; speedup vs baseline: 1.1955x; 1.1092x over previous
//
#include <hip/hip_runtime.h>

#define EPS 1e-6f

typedef __attribute__((ext_vector_type(8))) short bf16x8;
typedef __attribute__((ext_vector_type(4))) float f32x4;
typedef __attribute__((ext_vector_type(8))) unsigned short ushort8;

#define AS1(p) ((const __attribute__((address_space(1))) void*)(p))
#define AS3(p) ((__attribute__((address_space(3))) void*)(p))

__device__ inline unsigned int fkey(float f) {
  unsigned int u = __float_as_uint(f);
  return (u & 0x80000000u) ? ~u : (u | 0x80000000u);
}
// inverse of fkey: recover the exact fp32 bits
__device__ inline float inv_fkey(unsigned int k) {
  unsigned int u = (k & 0x80000000u) ? (k & 0x7fffffffu) : ~k;
  return __uint_as_float(u);
}

__device__ inline unsigned long long shfl_xor_u64(unsigned long long v, int mask) {
  unsigned int lo = (unsigned int)(v & 0xffffffffull);
  unsigned int hi = (unsigned int)(v >> 32);
  lo = (unsigned int)__shfl_xor((int)lo, mask);
  hi = (unsigned int)__shfl_xor((int)hi, mask);
  return (((unsigned long long)hi) << 32) | lo;
}

__device__ inline unsigned short f2bf(float f) {  // RNE fp32 -> bf16
  unsigned int u = __float_as_uint(f);
  u += 0x7fffu + ((u >> 16) & 1u);
  return (unsigned short)(u >> 16);
}
__device__ inline float bf2f(unsigned short h) {
  return __uint_as_float(((unsigned int)h) << 16);
}

// LDS byte-offset of a __shared__ address (AS3 pointers are 32-bit)
__device__ inline unsigned lds_off(const void* p) {
  return (unsigned)(unsigned long long)(__attribute__((address_space(3))) const void*)p;
}

// asm ds_read_b128 with immediate offset: compiler-untracked (we control lgkmcnt)
template<int OFF>
__device__ inline bf16x8 ds_read128(unsigned addr) {
  bf16x8 r;
  asm volatile("ds_read_b128 %0, %1 offset:%2" : "=v"(r) : "v"(addr), "i"(OFF));
  return r;
}

// asm global f32 load with immediate offset (keeps compiler vmcnt accounting clean)
template<int OFF>
__device__ inline float gload_f32(unsigned long long a) {
  float r;
  asm volatile("global_load_dword %0, %1, off offset:%2" : "=v"(r) : "v"(a), "i"(OFF));
  return r;
}

// ---------------- prep: splits + codebook norms + loss zero (one kernel) ----------------
__global__ __launch_bounds__(256) void prep_kernel(
    const float* __restrict__ x, const float* __restrict__ cbs,
    unsigned short* __restrict__ Rhi, unsigned short* __restrict__ Rlo,
    unsigned short* __restrict__ CBhi, unsigned short* __restrict__ CBlo,
    float* __restrict__ cbsq, float* __restrict__ loss_out) {
  constexpr size_t M = 32768, D = 512, C = 1024, Q = 8;
  const size_t nthreads = (size_t)gridDim.x * 256;
  const size_t gtid = (size_t)blockIdx.x * 256 + threadIdx.x;
  const int lane = threadIdx.x & 63;
  const int w = threadIdx.x >> 6;

  for (size_t i = gtid; i < M * D / 8; i += nthreads) {
    size_t off = i * 8;
    float4 v0 = *(const float4*)(x + off);
    float4 v1 = *(const float4*)(x + off + 4);
    float v[8] = {v0.x, v0.y, v0.z, v0.w, v1.x, v1.y, v1.z, v1.w};
    ushort8 h, l;
    #pragma unroll
    for (int j = 0; j < 8; j++) {
      unsigned short hh = f2bf(v[j]);
      h[j] = hh;
      l[j] = f2bf(v[j] - bf2f(hh));
    }
    *(ushort8*)(Rhi + off) = h;
    *(ushort8*)(Rlo + off) = l;
  }
  for (size_t i = gtid; i < Q * C * D / 8; i += nthreads) {
    size_t off = i * 8;
    float4 v0 = *(const float4*)(cbs + off);
    float4 v1 = *(const float4*)(cbs + off + 4);
    float v[8] = {v0.x, v0.y, v0.z, v0.w, v1.x, v1.y, v1.z, v1.w};
    ushort8 h, l;
    #pragma unroll
    for (int j = 0; j < 8; j++) {
      unsigned short hh = f2bf(v[j]);
      h[j] = hh;
      l[j] = f2bf(v[j] - bf2f(hh));
    }
    *(ushort8*)(CBhi + off) = h;
    *(ushort8*)(CBlo + off) = l;
  }
  for (int row = blockIdx.x * 4 + w; row < (int)(Q * C); row += gridDim.x * 4) {
    const float4* p = (const float4*)(cbs + (size_t)row * 512);
    float4 v0 = p[lane];
    float4 v1 = p[lane + 64];
    float s = v0.x*v0.x + v0.y*v0.y + v0.z*v0.z + v0.w*v0.w
            + v1.x*v1.x + v1.y*v1.y + v1.z*v1.z + v1.w*v1.w;
    #pragma unroll
    for (int off = 32; off; off >>= 1) s += __shfl_xor(s, off);
    if (lane == 0) cbsq[row] = s;
  }
  if (blockIdx.x == 0 && threadIdx.x < (int)Q) loss_out[threadIdx.x] = 0.f;
}

#define BARRIER  asm volatile("s_barrier" ::: "memory")
#define SCHEDB   __builtin_amdgcn_sched_barrier(0)
#define LGKM(N)  asm volatile("s_waitcnt lgkmcnt(" #N ")" ::: "memory")
#define VMC(N)   asm volatile("s_waitcnt vmcnt(" #N ")" ::: "memory")
#define MFMA1(d, a, b) d = __builtin_amdgcn_mfma_f32_16x16x32_bf16(a, b, d, 0, 0, 0)

// ---------------- fused ALL-STAGES kernel: cross-phase read-ahead schedule -------------
// R11: each phase reads the frags for the NEXT phase's MFMA quadrant; the wait is a
// counted lgkmcnt(4) that retires reads issued a FULL PHASE (~600cy) earlier -- the
// R8 defect (same-phase issue->lgkm(0), a 400-800cy unhidden LDS burst) is gone.
// Read schedule: P0->B23(t), P1->A23(t), P2->A01(t+1), P3->B01(t+1); quadrants
// Q0=A01*B01, Q1=A01*B23, Q2=A23*B23, Q3=A23*B01. A01/B01 register sets are [2]-
// double-buffered across the iter boundary (literal set index via macro). Barriers
// 8->4 per K-step. Cross-wave staging visibility: counted vmcnt(4) BEFORE P1's
// barrier retires stage(t+1) in every wave; the barrier propagates it, so P2/P3's
// reads of buf(t+1) are race-free. FIFO traces verified for prologue, steady state,
// and tails (t=62: vmcnt(0); t=63: no t+1 reads, lgkm(0)).
__global__ __launch_bounds__(512, 2) void stage_kernel(
    const float* __restrict__ x, const float* __restrict__ cbs,
    unsigned short* __restrict__ Rhi, unsigned short* __restrict__ Rlo,
    const unsigned short* __restrict__ CBhi, const unsigned short* __restrict__ CBlo,
    const float* __restrict__ cbsq, float* __restrict__ qout,
    float* __restrict__ idx_out, float* __restrict__ loss_out) {
  __shared__ unsigned short As[3][2][128 * 32];    // [buf][hi/lo] 48 KB
  __shared__ unsigned short Bs[3][2][256 * 32];    // [buf][hi/lo] 96 KB
  __shared__ unsigned long long bestLDS[4][128];   // 4 KB
  __shared__ float ls[8];

  const int tid = threadIdx.x;
  const int lane = tid & 63;
  const int w = tid >> 6;              // 0..7
  const int wr = w >> 2, wc = w & 3;   // wave grid 2 (rows) x 4 (cols)
  const int row0 = blockIdx.x * 128;

  // staging: lane -> (row-in-chunk rw, LDS slot oq); global octet pre-swizzled
  const int rw = lane >> 2, oq = lane & 3;
  const int o_sw = (oq - rw - (rw >> 2)) & 3;
  // fragment read: lane -> (row m, k-octet g); swizzled slot
  const int m = lane & 15, g = lane >> 4;
  const int f_sw8 = ((g + m + (m >> 2)) & 3) * 8;

  // global staging base pointers (per-lane); A constant across stages
  const unsigned short* pAhi = Rhi + (size_t)(row0 + w * 16 + rw) * 512 + o_sw * 8;
  const unsigned short* pAlo = Rlo + (size_t)(row0 + w * 16 + rw) * 512 + o_sw * 8;

  for (int qi = 0; qi < 8; ++qi) {
    const int last = (qi == 7);
    const size_t cbo = (size_t)qi * 524288;  // C*D
    const unsigned short* pBhi = CBhi + cbo + (size_t)(w * 32 + rw) * 512 + o_sw * 8;
    const unsigned short* pBlo = CBlo + cbo + (size_t)(w * 32 + rw) * 512 + o_sw * 8;
    const float* cq_base = cbsq + (qi << 10);
    const float* cbq_f32 = cbs + cbo;

    // LDS read base addresses (byte offsets), buf 0
    unsigned aA = lds_off(&As[0][0][(wr * 64 + m) * 32 + f_sw8]);
    unsigned aB = lds_off(&Bs[0][0][(wc * 64 + m) * 32 + f_sw8]);

    unsigned long long best[4][4];
    #pragma unroll
    for (int mi = 0; mi < 4; mi++)
      #pragma unroll
      for (int r = 0; r < 4; r++) best[mi][r] = ~0ull;

    auto stageA = [&](int buf, int t) {
      const size_t ko = (size_t)((t & 15) * 32);
      __builtin_amdgcn_global_load_lds(AS1(pAhi + ko), AS3(&As[buf][0][w * 512]), 16, 0, 0);
      __builtin_amdgcn_global_load_lds(AS1(pAlo + ko), AS3(&As[buf][1][w * 512]), 16, 0, 0);
    };
    auto stageB1 = [&](int buf, int t) {
      const size_t ko = (size_t)((t & 15) * 32);
      const size_t cof = (size_t)((t >> 4) * 256) * 512;
      unsigned short* dBh = &Bs[buf][0][w * 1024];
      __builtin_amdgcn_global_load_lds(AS1(pBhi + cof + ko), AS3(dBh), 16, 0, 0);
      __builtin_amdgcn_global_load_lds(AS1(pBhi + cof + ko + 8192), AS3(dBh + 512), 16, 0, 0);
    };
    auto stageB2 = [&](int buf, int t) {
      const size_t ko = (size_t)((t & 15) * 32);
      const size_t cof = (size_t)((t >> 4) * 256) * 512;
      unsigned short* dBl = &Bs[buf][1][w * 1024];
      __builtin_amdgcn_global_load_lds(AS1(pBlo + cof + ko), AS3(dBl), 16, 0, 0);
      __builtin_amdgcn_global_load_lds(AS1(pBlo + cof + ko + 8192), AS3(dBl + 512), 16, 0, 0);
    };

    // stage top: all waves done with previous stage (LDS reuse safe)
    __syncthreads();

    // cq via asm loads; vmcnt(0) also retires the previous epilogue's stores
    float cq[4][4];
    {
      unsigned long long cqp = (unsigned long long)(cq_base + wc * 64 + m);
      cq[0][0] = gload_f32<0>(cqp);    cq[0][1] = gload_f32<64>(cqp);
      cq[0][2] = gload_f32<128>(cqp);  cq[0][3] = gload_f32<192>(cqp);
      cq[1][0] = gload_f32<1024>(cqp); cq[1][1] = gload_f32<1088>(cqp);
      cq[1][2] = gload_f32<1152>(cqp); cq[1][3] = gload_f32<1216>(cqp);
      cq[2][0] = gload_f32<2048>(cqp); cq[2][1] = gload_f32<2112>(cqp);
      cq[2][2] = gload_f32<2176>(cqp); cq[2][3] = gload_f32<2240>(cqp);
      cq[3][0] = gload_f32<3072>(cqp); cq[3][1] = gload_f32<3136>(cqp);
      cq[3][2] = gload_f32<3200>(cqp); cq[3][3] = gload_f32<3264>(cqp);
      VMC(0);
    }

    // fragment register sets: A01/B01 double-buffered (literal set idx), A23/B23 single
    bf16x8 A01h[2][2], A01l[2][2], B01h[2][2], B01l[2][2];
    bf16x8 A23h[2], A23l[2], B23h[2], B23l[2];
    f32x4 acc[4][4];
    int bn = 0;   // buf holding tile t
    int bst = 2;  // buf target for stage(t+2)

    // ---- prologue: fill bufs 0,1; read A01(0),B01(0) into set 0 ----
    stageA(0, 0); stageB1(0, 0); stageB2(0, 0);
    stageA(1, 1); stageB1(1, 1); stageB2(1, 1);
    VMC(6);                       // tile 0 resident (6 left = stage(1))
    BARRIER; SCHEDB;
    A01h[0][0] = ds_read128<0>(aA);     A01h[0][1] = ds_read128<1024>(aA);
    A01l[0][0] = ds_read128<8192>(aA);  A01l[0][1] = ds_read128<9216>(aA);
    B01h[0][0] = ds_read128<0>(aB);     B01h[0][1] = ds_read128<1024>(aB);
    B01l[0][0] = ds_read128<16384>(aB); B01l[0][1] = ds_read128<17408>(aB);
    LGKM(4);                      // A01(0) retired; B01(0) stays outstanding (4)
    SCHEDB;

#define K_ITER(T, CS, RD)                                                         \
  {                                                                               \
    const int t_ = (T);                                                           \
    const int kk_ = t_ & 15;                                                      \
    const int s_ = (bn == 2) ? -2 : 1;                                            \
    const unsigned aA2 = aA + s_ * 16384, aB2 = aB + s_ * 32768;                  \
    /* P0: rd B23(t) | stage A(t+2) | BAR | lgkm4 (retire B01(t)) | Q0 */         \
    B23h[0] = ds_read128<2048>(aB);  B23h[1] = ds_read128<3072>(aB);              \
    B23l[0] = ds_read128<18432>(aB); B23l[1] = ds_read128<19456>(aB);             \
    if (t_ < 62) stageA(bst, t_ + 2);                                             \
    if (kk_ == 0) {                                                               \
      _Pragma("unroll") for (int mi = 0; mi < 4; mi++)                            \
        _Pragma("unroll") for (int ni = 0; ni < 4; ni++)                          \
          acc[mi][ni] = (f32x4){0.f, 0.f, 0.f, 0.f};                              \
    }                                                                             \
    BARRIER; LGKM(4); SCHEDB;                                                     \
    __builtin_amdgcn_s_setprio(1);                                                \
    _Pragma("unroll") for (int i = 0; i < 2; i++)                                 \
      _Pragma("unroll") for (int j = 0; j < 2; j++)                               \
        MFMA1(acc[i][j], A01h[CS][i], B01h[CS][j]);                               \
    _Pragma("unroll") for (int i = 0; i < 2; i++)                                 \
      _Pragma("unroll") for (int j = 0; j < 2; j++)                               \
        MFMA1(acc[i][j], A01h[CS][i], B01l[CS][j]);                               \
    _Pragma("unroll") for (int i = 0; i < 2; i++)                                 \
      _Pragma("unroll") for (int j = 0; j < 2; j++)                               \
        MFMA1(acc[i][j], A01l[CS][i], B01h[CS][j]);                               \
    __builtin_amdgcn_s_setprio(0);                                                \
    /* P1: rd A23(t) | stage B1(t+2) | vmcnt | BAR | lgkm4 (retire B23) | Q1 */   \
    A23h[0] = ds_read128<2048>(aA);  A23h[1] = ds_read128<3072>(aA);              \
    A23l[0] = ds_read128<10240>(aA); A23l[1] = ds_read128<11264>(aA);             \
    if (t_ < 62) { stageB1(bst, t_ + 2); VMC(4); }                                \
    else if (t_ == 62) VMC(0);                                                    \
    BARRIER; LGKM(4); SCHEDB;                                                     \
    __builtin_amdgcn_s_setprio(1);                                                \
    _Pragma("unroll") for (int i = 0; i < 2; i++)                                 \
      _Pragma("unroll") for (int j = 0; j < 2; j++)                               \
        MFMA1(acc[i][2 + j], A01h[CS][i], B23h[j]);                               \
    _Pragma("unroll") for (int i = 0; i < 2; i++)                                 \
      _Pragma("unroll") for (int j = 0; j < 2; j++)                               \
        MFMA1(acc[i][2 + j], A01h[CS][i], B23l[j]);                               \
    _Pragma("unroll") for (int i = 0; i < 2; i++)                                 \
      _Pragma("unroll") for (int j = 0; j < 2; j++)                               \
        MFMA1(acc[i][2 + j], A01l[CS][i], B23h[j]);                               \
    __builtin_amdgcn_s_setprio(0);                                                \
    /* P2: rd A01(t+1) | stage B2(t+2) | BAR | lgkm4 (retire A23) | Q2 */         \
    if (t_ < 63) {                                                                \
      A01h[RD][0] = ds_read128<0>(aA2);    A01h[RD][1] = ds_read128<1024>(aA2);   \
      A01l[RD][0] = ds_read128<8192>(aA2); A01l[RD][1] = ds_read128<9216>(aA2);   \
    }                                                                             \
    if (t_ < 62) stageB2(bst, t_ + 2);                                            \
    BARRIER;                                                                      \
    if (t_ < 63) { LGKM(4); } else { LGKM(0); }                                   \
    SCHEDB;                                                                       \
    __builtin_amdgcn_s_setprio(1);                                                \
    _Pragma("unroll") for (int i = 0; i < 2; i++)                                 \
      _Pragma("unroll") for (int j = 0; j < 2; j++)                               \
        MFMA1(acc[2 + i][2 + j], A23h[i], B23h[j]);                               \
    _Pragma("unroll") for (int i = 0; i < 2; i++)                                 \
      _Pragma("unroll") for (int j = 0; j < 2; j++)                               \
        MFMA1(acc[2 + i][2 + j], A23h[i], B23l[j]);                               \
    _Pragma("unroll") for (int i = 0; i < 2; i++)                                 \
      _Pragma("unroll") for (int j = 0; j < 2; j++)                               \
        MFMA1(acc[2 + i][2 + j], A23l[i], B23h[j]);                               \
    __builtin_amdgcn_s_setprio(0);                                                \
    /* P3: rd B01(t+1) | BAR | lgkm4 (retire A01(t+1)) | Q3 | fold */             \
    if (t_ < 63) {                                                                \
      B01h[RD][0] = ds_read128<0>(aB2);     B01h[RD][1] = ds_read128<1024>(aB2);  \
      B01l[RD][0] = ds_read128<16384>(aB2); B01l[RD][1] = ds_read128<17408>(aB2); \
    }                                                                             \
    BARRIER;                                                                      \
    if (t_ < 63) { LGKM(4); } else { LGKM(0); }                                   \
    SCHEDB;                                                                       \
    __builtin_amdgcn_s_setprio(1);                                                \
    _Pragma("unroll") for (int i = 0; i < 2; i++)                                 \
      _Pragma("unroll") for (int j = 0; j < 2; j++)                               \
        MFMA1(acc[2 + i][j], A23h[i], B01h[CS][j]);                               \
    _Pragma("unroll") for (int i = 0; i < 2; i++)                                 \
      _Pragma("unroll") for (int j = 0; j < 2; j++)                               \
        MFMA1(acc[2 + i][j], A23h[i], B01l[CS][j]);                               \
    _Pragma("unroll") for (int i = 0; i < 2; i++)                                 \
      _Pragma("unroll") for (int j = 0; j < 2; j++)                               \
        MFMA1(acc[2 + i][j], A23l[i], B01h[CS][j]);                               \
    __builtin_amdgcn_s_setprio(0);                                                \
    if (kk_ == 15) {                                                              \
      const int ct_ = t_ >> 4;                                                    \
      const unsigned colb = ct_ * 256 + wc * 64 + m;                              \
      _Pragma("unroll") for (int mi = 0; mi < 4; mi++)                            \
        _Pragma("unroll") for (int r = 0; r < 4; r++) {                           \
          _Pragma("unroll") for (int ni = 0; ni < 4; ni++) {                      \
            float d2 = fmaf(-2.f, acc[mi][ni][r], cq[ct_][ni]);                   \
            unsigned long long p =                                                \
                (((unsigned long long)fkey(d2)) << 32) | (colb + ni * 16);        \
            if (p < best[mi][r]) best[mi][r] = p;                                 \
          }                                                                       \
        }                                                                         \
    }                                                                             \
    aA = aA2; aB = aB2;                                                           \
    bn = (bn == 2) ? 0 : bn + 1;                                                  \
    bst = (bst == 2) ? 0 : bst + 1;                                               \
  }

    for (int tp = 0; tp < 32; tp++) {
      K_ITER(tp * 2,     0, 1);   // consume set0, read set1
      K_ITER(tp * 2 + 1, 1, 0);   // consume set1, read set0
    }
#undef K_ITER

    // deferred cross-lane argmin reduce (over the 16 cols in each fragment)
    #pragma unroll
    for (int mi = 0; mi < 4; mi++)
      #pragma unroll
      for (int r = 0; r < 4; r++) {
        unsigned long long mn = best[mi][r];
        #pragma unroll
        for (int off = 1; off < 16; off <<= 1) {
          unsigned long long o = shfl_xor_u64(mn, off);
          if (o < mn) mn = o;
        }
        best[mi][r] = mn;
      }

    // publish per-row argmin quarters (wc = 0..3) to LDS
    if (m == 0) {
      #pragma unroll
      for (int mi = 0; mi < 4; mi++)
        #pragma unroll
        for (int r = 0; r < 4; r++)
          bestLDS[wc][wr * 64 + mi * 16 + g * 4 + r] = best[mi][r];
    }
    __syncthreads();

    // ---------------- rotate epilogue: 16 rows per wave ----------------
    float lossacc = 0.f;
    #pragma unroll 2
    for (int rr = 0; rr < 16; rr++) {
      const int row128 = w * 16 + rr;
      unsigned long long mn = bestLDS[0][row128];
      #pragma unroll
      for (int q2 = 1; q2 < 4; q2++) {
        unsigned long long o = bestLDS[q2][row128];
        if (o < mn) mn = o;
      }
      const int c = (int)(mn & 0xffffffffu);
      const int row = row0 + row128;
      if (lane == 0) idx_out[(size_t)row * 8 + qi] = (float)c;

      // scalars recovered from the GEMM fold (no elementwise recompute):
      const float qq = cq_base[c];                       // ||q||^2, fp32-exact
      const float d2b = inv_fkey((unsigned)(mn >> 32));  // d2 = qq - 2*(r.q)
      const float zq = (qq - d2b) * 0.5f;                // r.q as the MFMA computed it

      const size_t base = (size_t)row * 512 + lane * 8;
      ushort8 h = *(const ushort8*)(Rhi + base);
      ushort8 l = *(const ushort8*)(Rlo + base);
      const float* qrow = cbq_f32 + (size_t)c * 512 + lane * 8;
      float4 q0 = *(const float4*)qrow;
      float4 q1 = *(const float4*)(qrow + 4);
      float z[8], q[8] = {q0.x, q0.y, q0.z, q0.w, q1.x, q1.y, q1.z, q1.w};
      #pragma unroll
      for (int j = 0; j < 8; j++) z[j] = bf2f(h[j]) + bf2f(l[j]);

      float zz = 0.f;
      #pragma unroll
      for (int j = 0; j < 8; j++) zz = fmaf(z[j], z[j], zz);
      #pragma unroll
      for (int off = 32; off; off >>= 1) zz += __shfl_xor(zz, off);

      float nz = sqrtf(zz), nq = sqrtf(qq);
      float inz = 1.f / (nz + EPS), inq = 1.f / (nq + EPS);
      float ns  = sqrtf(zz*inz*inz + 2.f*zq*inz*inq + qq*inq*inq);
      float ins = 1.f / ns;
      float zw  = (zz*inz + zq*inq) * ins;
      float zzn = zz * inz;
      float scale = nq * inz;
      float az = scale * (1.f - 2.f * zw * ins * inz);
      float aq = scale * (2.f * zzn - 2.f * zw * ins) * inq;

      if (!last) {
        #pragma unroll
        for (int j = 0; j < 8; j++) {
          float r = z[j] - (az * z[j] + aq * q[j]);
          unsigned short hh = f2bf(r);
          h[j] = hh;
          l[j] = f2bf(r - bf2f(hh));
        }
        *(ushort8*)(Rhi + base) = h;
        *(ushort8*)(Rlo + base) = l;
      } else {
        float4 x0 = *(const float4*)(x + base);
        float4 x1 = *(const float4*)(x + base + 4);
        float xv[8] = {x0.x, x0.y, x0.z, x0.w, x1.x, x1.y, x1.z, x1.w};
        float o[8];
        #pragma unroll
        for (int j = 0; j < 8; j++) {
          float r = z[j] - (az * z[j] + aq * q[j]);
          o[j] = xv[j] - r;
        }
        *(float4*)(qout + base)     = (float4){o[0], o[1], o[2], o[3]};
        *(float4*)(qout + base + 4) = (float4){o[4], o[5], o[6], o[7]};
      }
      lossacc += (zz - 2.f * zq + qq);
    }
    if (lane == 0) ls[w] = lossacc;
    __syncthreads();
    if (tid == 0)
      atomicAdd(loss_out + qi, (ls[0] + ls[1] + ls[2] + ls[3] +
                                ls[4] + ls[5] + ls[6] + ls[7]) *
                               (1.f / (32768.f * 512.f)));
  }
}

extern "C" void kernel_launch(void* const* d_in, const int* in_sizes, int n_in,
                              void* d_out, int out_size, void* d_ws, size_t ws_size,
                              hipStream_t stream) {
  const float* x   = (const float*)d_in[0];   // [16, 2048, 512]
  const float* cbs = (const float*)d_in[1];   // [8, 1024, 512]
  float* out = (float*)d_out;
  const size_t M = 32768, D = 512, Q = 8, C = 1024;
  float* qout     = out;                 // [M, D]
  float* idx_out  = out + M * D;         // [M, Q] (as float)
  float* loss_out = idx_out + M * Q;     // [Q]

  // ws: Rhi 32M | Rlo 32M | CBhi 8M | CBlo 8M | cbsq 32K
  unsigned short* Rhi  = (unsigned short*)d_ws;
  unsigned short* Rlo  = Rhi + M * D;
  unsigned short* CBhi = Rlo + M * D;
  unsigned short* CBlo = CBhi + Q * C * D;
  float* cbsq = (float*)(CBlo + Q * C * D);

  prep_kernel<<<512, 256, 0, stream>>>(x, cbs, Rhi, Rlo, CBhi, CBlo, cbsq, loss_out);

  stage_kernel<<<256, 512, 0, stream>>>(
      x, cbs, Rhi, Rlo, CBhi, CBlo, cbsq, qout, idx_out, loss_out);
}